// Round 2
// baseline (317.166 us; speedup 1.0000x reference)
//
#include <hip/hip_runtime.h>
#include <hip/hip_bf16.h>
#include <cstdint>

// Problem constants
#define B_ 4
#define N_ 2048
#define C_ 768
#define H_ 12
#define D_ 64
// SCALE = D^-0.5 = 0.125; folded exp2 scale = 0.125 * log2(e)
#define QSCALE 0.18033688011112042f

typedef __bf16 bf16x8 __attribute__((ext_vector_type(8)));
typedef float f32x4 __attribute__((ext_vector_type(4)));
typedef float f32x16 __attribute__((ext_vector_type(16)));

// RNE float -> bf16 bits (branchless; inputs are finite)
__device__ __forceinline__ unsigned f2bs(float x) {
  unsigned u = __builtin_bit_cast(unsigned, x);
  unsigned r = (u + 0x7fffu + ((u >> 16) & 1u)) >> 16;
  return r;
}

__device__ __forceinline__ bf16x8 ldb8(const unsigned short* p) {
  return __builtin_bit_cast(bf16x8, *(const uint4*)p);
}

__device__ __forceinline__ f32x4 mfma16(bf16x8 a, bf16x8 b, f32x4 c) {
  return __builtin_amdgcn_mfma_f32_16x16x32_bf16(a, b, c, 0, 0, 0);
}

__device__ __forceinline__ f32x16 mfma32(bf16x8 a, bf16x8 b, f32x16 c) {
  return __builtin_amdgcn_mfma_f32_32x32x16_bf16(a, b, c, 0, 0, 0);
}

// async global->LDS, 16B per lane. lds base must be wave-uniform; HW deposits
// lane i at lds + i*16 (m97/m104 semantics).
__device__ __forceinline__ void async16(const unsigned short* g, unsigned short* l) {
  __builtin_amdgcn_global_load_lds(
      (const __attribute__((address_space(1))) unsigned int*)g,
      (__attribute__((address_space(3))) unsigned int*)l, 16, 0, 0);
}

// ---------------- fused prep: x/W f32->bf16 casts + uc row means ----------------
// blocks [0,18432): convert x_q/x_k/x_v (6144 blocks each)
// blocks [18432,20736): convert Wq/Wk/Wv/Wp (576 blocks each)
// blocks [20736,22784): uc[row] = mean(x_u row) (2048 blocks, 4 rows each)
__global__ void prep_kernel(
    const float* __restrict__ xq, const float* __restrict__ xk,
    const float* __restrict__ xv, const float* __restrict__ xu,
    const float* __restrict__ Wq, const float* __restrict__ Wk,
    const float* __restrict__ Wv, const float* __restrict__ Wp,
    unsigned short* __restrict__ dxq, unsigned short* __restrict__ dxk,
    unsigned short* __restrict__ dxv,
    unsigned short* __restrict__ dwq, unsigned short* __restrict__ dwk,
    unsigned short* __restrict__ dwv, unsigned short* __restrict__ dwp,
    float* __restrict__ uc) {
  const int id = blockIdx.x;
  if (id < 18432) {
    const float* s = (id < 6144) ? xq : (id < 12288) ? xk : xv;
    unsigned short* d = (id < 6144) ? dxq : (id < 12288) ? dxk : dxv;
    int i = ((id % 6144) * 256 + threadIdx.x) * 4;
    float4 v = *(const float4*)(s + i);
    ushort4 h;
    h.x = (unsigned short)f2bs(v.x); h.y = (unsigned short)f2bs(v.y);
    h.z = (unsigned short)f2bs(v.z); h.w = (unsigned short)f2bs(v.w);
    *(ushort4*)(d + i) = h;
  } else if (id < 20736) {
    int sub = id - 18432;
    int which = sub / 576;
    const float* s = (which == 0) ? Wq : (which == 1) ? Wk : (which == 2) ? Wv : Wp;
    unsigned short* d = (which == 0) ? dwq : (which == 1) ? dwk : (which == 2) ? dwv : dwp;
    int i = ((sub % 576) * 256 + threadIdx.x) * 4;
    float4 v = *(const float4*)(s + i);
    ushort4 h;
    h.x = (unsigned short)f2bs(v.x); h.y = (unsigned short)f2bs(v.y);
    h.z = (unsigned short)f2bs(v.z); h.w = (unsigned short)f2bs(v.w);
    *(ushort4*)(d + i) = h;
  } else {
    int sub = id - 20736;
    int w = threadIdx.x >> 6, lane = threadIdx.x & 63;
    int row = sub * 4 + w;
    const float* p = xu + (size_t)row * C_;
    float s = 0.f;
#pragma unroll
    for (int i = 0; i < 3; ++i) {
      float4 v = *(const float4*)(p + (i * 64 + lane) * 4);
      s += v.x + v.y + v.z + v.w;
    }
#pragma unroll
    for (int off = 1; off < 64; off <<= 1) s += __shfl_xor(s, off);
    if (lane == 0) uc[row] = s * (1.f / 768.f);
  }
}

// ---------------- GEMM mainloop (128x128 tile, BK=64, async16 staging) -------------
// A [8192 x 768] bf16 row-major, W [768 x 768] bf16 row-major (NT gemm).
// LDS: two 32-col panels per BK=64 tile (panel kk at kk*4096 shorts, [row][32]).
// Granule g = s*256+tid: dest shorts [g*8..g*8+8), src row=(g>>2)&127,
// col=((g>>9)<<5)|((g&3)<<3).  (R5/R7-measured structure.)
__device__ __forceinline__ void gemm_mainloop(
    const unsigned short* __restrict__ A, const unsigned short* __restrict__ W,
    int m0, int n0, unsigned short* Al, unsigned short* Bl,
    int tid, int wm, int wn, int quad, int id15, f32x4 (*acc)[4]) {
  const int wb = tid & 192;                        // wave-uniform granule base
  const unsigned short* ap[4];
  const unsigned short* bp[4];
#pragma unroll
  for (int s = 0; s < 4; ++s) {
    int g = s * 256 + tid;
    int row = (g >> 2) & 127;
    int col = ((g >> 9) << 5) | ((g & 3) << 3);
    ap[s] = A + (size_t)(m0 + row) * C_ + col;
    bp[s] = W + (size_t)(n0 + row) * C_ + col;
  }

  for (int kt = 0; kt < C_; kt += 64) {
    __syncthreads();
#pragma unroll
    for (int s = 0; s < 4; ++s) {
      async16(ap[s] + kt, Al + (s * 256 + wb) * 8);
      async16(bp[s] + kt, Bl + (s * 256 + wb) * 8);
    }
    __syncthreads();

#pragma unroll
    for (int kk = 0; kk < 2; ++kk) {
      bf16x8 af[4], bfr[4];
#pragma unroll
      for (int i = 0; i < 4; ++i)
        af[i]  = ldb8(&Al[kk * 4096 + (wm + i * 16 + id15) * 32 + quad * 8]);
#pragma unroll
      for (int j = 0; j < 4; ++j)
        bfr[j] = ldb8(&Bl[kk * 4096 + (wn + j * 16 + id15) * 32 + quad * 8]);
#pragma unroll
      for (int i = 0; i < 4; ++i)
#pragma unroll
        for (int j = 0; j < 4; ++j)
          acc[i][j] = mfma16(af[i], bfr[j], acc[i][j]);
    }
  }
}

// ---------------- fused QKV projection (XCD-swizzled 1D grid, 1152 blocks) ---------
// Blocks sharing an A-tile (all 6 n) are placed on the SAME XCD so its L2 serves
// the A re-reads (R6 profile: FETCH 169 MB vs ~41 MB ideal = cross-XCD duplication).
// z=0: Q = x_q@Wq^T * QSCALE*uc; z=1: K; z=2: V^T via LDS transpose, coalesced.
#define TSTR 136   // transpose LDS row stride (shorts): 272 B, 16B-aligned rows
__global__ __launch_bounds__(256, 3) void gemm_qkv(
    const unsigned short* __restrict__ xq, const unsigned short* __restrict__ xk,
    const unsigned short* __restrict__ xv,
    const unsigned short* __restrict__ wq, const unsigned short* __restrict__ wk,
    const unsigned short* __restrict__ wv,
    unsigned short* __restrict__ oq, unsigned short* __restrict__ ok,
    unsigned short* __restrict__ ov, const float* __restrict__ uc) {
  __shared__ __align__(16) unsigned short S[128 * TSTR];   // 34816 B; aliases Al/Bl
  unsigned short* Al = S;
  unsigned short* Bl = S + 8192;
  const int tid = threadIdx.x;
  const int w = tid >> 6, lane = tid & 63, quad = lane >> 4, id15 = lane & 15;
  const int wm = (w >> 1) << 6, wn = (w & 1) << 6;
  // XCD swizzle: xcd = id&7; within an XCD, n varies fastest for fixed (z,m)
  const int id = blockIdx.x;
  const int xcd = id & 7, slot = id >> 3;          // slot 0..143
  const int n0 = (slot % 6) << 7;
  const int gz = xcd * 24 + slot / 6;              // 0..191 = (z,m) pairs
  const int z = gz >> 6, m0 = (gz & 63) << 7;

  const unsigned short* A = (z == 0) ? xq : (z == 1) ? xk : xv;
  const unsigned short* W = (z == 0) ? wq : (z == 1) ? wk : wv;

  f32x4 acc[4][4] = {};
  gemm_mainloop(A, W, m0, n0, Al, Bl, tid, wm, wn, quad, id15, acc);

  if (z == 2) {
    // transpose through LDS: S[gn_local][n_local], then coalesced row writes
    __syncthreads();
#pragma unroll
    for (int i = 0; i < 4; ++i)
#pragma unroll
      for (int j = 0; j < 4; ++j) {
        uint2 u;
        u.x = f2bs(acc[i][j][0]) | (f2bs(acc[i][j][1]) << 16);
        u.y = f2bs(acc[i][j][2]) | (f2bs(acc[i][j][3]) << 16);
        *(uint2*)&S[(wn + j * 16 + id15) * TSTR + wm + i * 16 + quad * 4] = u;
      }
    __syncthreads();
    const int b = m0 >> 11, nb = m0 & (N_ - 1);
#pragma unroll
    for (int s = 0; s < 8; ++s) {
      int c = s * 256 + tid;               // 2048 chunks of 8 shorts
      int row = c >> 4, o = (c & 15) << 3;
      *(uint4*)(ov + (size_t)(b * C_ + n0 + row) * N_ + nb + o) = *(const uint4*)&S[row * TSTR + o];
    }
    return;
  }

#pragma unroll
  for (int i = 0; i < 4; ++i) {
#pragma unroll
    for (int j = 0; j < 4; ++j) {
#pragma unroll
      for (int r = 0; r < 4; ++r) {
        int gm = m0 + wm + i * 16 + quad * 4 + r;   // global row (b*N + n)
        int gn = n0 + wn + j * 16 + id15;           // global out channel
        float v = acc[i][j][r];
        if (z == 0) {
          v *= QSCALE * uc[gm];
          oq[(size_t)gm * C_ + gn] = (unsigned short)f2bs(v);
        } else {
          ok[(size_t)gm * C_ + gn] = (unsigned short)f2bs(v);
        }
      }
    }
  }
}

// ---------------- output projection: out = ao@Wp^T + bp, f32 ----------------
// Tile 64(M) x 128(N), BK=64 -> 768 blocks = 3/CU (was 384 = 1.5/CU tail).
// XCD swizzle: same-A-tile blocks (6 n) on one XCD.
__global__ __launch_bounds__(256, 4) void gemm_out(
    const unsigned short* __restrict__ ao, const unsigned short* __restrict__ wp,
    float* __restrict__ out, const float* __restrict__ bias) {
  __shared__ __align__(16) unsigned short Al[64 * 64];
  __shared__ __align__(16) unsigned short Bl[128 * 64];
  const int tid = threadIdx.x;
  const int w = tid >> 6, lane = tid & 63, quad = lane >> 4, id15 = lane & 15;
  const int wm = (w >> 1) << 5, wn = (w & 1) << 6;
  const int id = blockIdx.x;
  const int xcd = id & 7, slot = id >> 3;          // slot 0..95
  const int n0 = (slot % 6) << 7;
  const int m0 = (xcd * 16 + slot / 6) << 6;       // m-tile 0..127

  const int wb = tid & 192;
  const unsigned short* ap[2];
#pragma unroll
  for (int s = 0; s < 2; ++s) {                    // A: 64x64 tile, 512 granules
    int g = s * 256 + tid;
    int row = (g >> 2) & 63;
    int col = ((g >> 8) << 5) | ((g & 3) << 3);
    ap[s] = ao + (size_t)(m0 + row) * C_ + col;
  }
  const unsigned short* bp[4];
#pragma unroll
  for (int s = 0; s < 4; ++s) {                    // B: 128x64 tile, 1024 granules
    int g = s * 256 + tid;
    int row = (g >> 2) & 127;
    int col = ((g >> 9) << 5) | ((g & 3) << 3);
    bp[s] = wp + (size_t)(n0 + row) * C_ + col;
  }

  f32x4 acc[2][4] = {};
  for (int kt = 0; kt < C_; kt += 64) {
    __syncthreads();
#pragma unroll
    for (int s = 0; s < 2; ++s) async16(ap[s] + kt, Al + (s * 256 + wb) * 8);
#pragma unroll
    for (int s = 0; s < 4; ++s) async16(bp[s] + kt, Bl + (s * 256 + wb) * 8);
    __syncthreads();

#pragma unroll
    for (int kk = 0; kk < 2; ++kk) {
      bf16x8 af[2], bfr[4];
#pragma unroll
      for (int i = 0; i < 2; ++i)
        af[i]  = ldb8(&Al[kk * 2048 + (wm + i * 16 + id15) * 32 + quad * 8]);
#pragma unroll
      for (int j = 0; j < 4; ++j)
        bfr[j] = ldb8(&Bl[kk * 4096 + (wn + j * 16 + id15) * 32 + quad * 8]);
#pragma unroll
      for (int i = 0; i < 2; ++i)
#pragma unroll
        for (int j = 0; j < 4; ++j)
          acc[i][j] = mfma16(af[i], bfr[j], acc[i][j]);
    }
  }

#pragma unroll
  for (int i = 0; i < 2; ++i) {
#pragma unroll
    for (int j = 0; j < 4; ++j) {
#pragma unroll
      for (int r = 0; r < 4; ++r) {
        int gm = m0 + wm + i * 16 + quad * 4 + r;
        int gn = n0 + wn + j * 16 + id15;
        out[(size_t)gm * C_ + gn] = acc[i][j][r] + bias[gn];
      }
    }
  }
}

// ---------------- Flash attention v3: K-only LDS, direct-L2 V, permlane -----------
// R1 post-mortem: __syncthreads' vmcnt(0) drain defeated the async split, and the
// LDS pipe (16 b128 frag reads + 16 bpermute + 4 writes per wave-iter) sat on the
// dependency path (~53us of pipe time). v3:
//  * V-frags read directly from vT (per-head KV = 512KB, L2-resident on its XCD;
//    common-mistake #7: don't stage L2-fit data). Deletes V staging + 8 ds_reads.
//  * raw s_barrier + lgkmcnt(0)-only wait (8-phase idiom): V-frag and next-K
//    global loads genuinely stay in flight across the barrier (T4/T14).
//  * v_permlane32_swap_b32 replaces 16 ds_bpermute + 16 cndmask with 8 VALU ops.
//    swap(a,b): a' = {a_lo | b_lo}, b' = {a_hi | b_hi} across the lane-32 split,
//    which is exactly the verified {hi?L2:Dw0, hi?Dw2:H0} pair from v2.
// C/D layout (m74/m101): col=lane&31, row=(reg&3)+8*(reg>>2)+4*(lane>>5).
#define KSTR 72   // K LDS row stride (shorts): 144 B
#define BUFO (64 * KSTR)        // K double-buffer stride (shorts); LDS = 18432 B
__global__ __launch_bounds__(256, 3) void attn_kernel(
    const unsigned short* __restrict__ Q, const unsigned short* __restrict__ Kk,
    const unsigned short* __restrict__ Vt, unsigned short* __restrict__ O) {
  __shared__ __align__(16) unsigned short Kl[2 * 64 * KSTR];  // 18432 B

  const int tid = threadIdx.x;
  const int w = tid >> 6, lane = tid & 63;
  const int i32 = lane & 31, hi = lane >> 5;
  const int id = blockIdx.x;
  const int xcd = id & 7, slot = id >> 3;          // slot 0..95
  const int bh = xcd * 6 + (slot >> 4);            // 0..47
  const int qt = slot & 15;
  const int b = bh / H_, h = bh % H_;
  const int q0 = qt * 128 + w * 32;                // 32 q-rows per wave

  // Q fragments (B-operand of QK^T): qf[s] = Q[q0+i32][d = s*16 + hi*8 + e]
  bf16x8 qf[4];
#pragma unroll
  for (int s = 0; s < 4; ++s)
    qf[s] = ldb8(Q + (size_t)(b * N_ + q0 + i32) * C_ + h * 64 + s * 16 + hi * 8);

  const uint4 onesu = {0x3F803F80u, 0x3F803F80u, 0x3F803F80u, 0x3F803F80u};
  const bf16x8 onesf = __builtin_bit_cast(bf16x8, onesu);

  f32x16 oacc0 = {}, oacc1 = {}, lacc = {};

  const size_t kbase = (size_t)(b * N_) * C_ + h * 64;
  const size_t vbase = (size_t)(b * C_ + h * 64) * N_;
  const int srow0 = tid >> 3, srow1 = 32 + (tid >> 3);
  const int sseg = (tid & 7) << 3;
  // V-frag base: lane reads vT row d = dh*32 + i32, k-slice ks*16 + hi*8
  const unsigned short* vp = Vt + vbase + (size_t)i32 * N_ + hi * 8;

  // Prologue: stage K tile 0 into buffer 0
  {
    uint4 a0 = *(const uint4*)(Kk + kbase + (size_t)srow0 * C_ + sseg);
    uint4 a1 = *(const uint4*)(Kk + kbase + (size_t)srow1 * C_ + sseg);
    *(uint4*)&Kl[srow0 * KSTR + sseg] = a0;
    *(uint4*)&Kl[srow1 * KSTR + sseg] = a1;
  }

  int cur = 0;
  for (int kc = 0; kc < N_; kc += 64) {
    // V-frags for THIS tile: direct from L2, issued first (latency hides under
    // QK^T + exp2; no vmcnt drain at the raw barrier below).
    uint4 vr[4][2];
#pragma unroll
    for (int ks = 0; ks < 4; ++ks) {
      vr[ks][0] = *(const uint4*)(vp + kc + ks * 16);
      vr[ks][1] = *(const uint4*)(vp + 32 * N_ + kc + ks * 16);
    }
    // next K tile -> regs (written to LDS after compute)
    const bool last = (kc + 64 >= N_);
    uint4 a0, a1;
    if (!last) {
      a0 = *(const uint4*)(Kk + kbase + (size_t)(kc + 64 + srow0) * C_ + sseg);
      a1 = *(const uint4*)(Kk + kbase + (size_t)(kc + 64 + srow1) * C_ + sseg);
    }

    // drain own LDS ops (prev writes + prev frag reads), then barrier.
    // NO vmcnt drain -- global loads above stay in flight (T4).
    asm volatile("s_waitcnt lgkmcnt(0)" ::: "memory");
    __builtin_amdgcn_s_barrier();

    const unsigned short* Kc = Kl + (cur ? BUFO : 0);
#pragma unroll
    for (int t = 0; t < 2; ++t) {        // k-row tile of 32 within the 64-row block
      // QK^T (S^T: rows = k, cols = q), contraction over D=64 in 4 ksteps
      f32x16 s16 = {};
#pragma unroll
      for (int s = 0; s < 4; ++s) {
        bf16x8 kf = ldb8(Kc + (t * 32 + i32) * KSTR + s * 16 + hi * 8);
        s16 = mfma32(kf, qf[s], s16);
      }
      // exp2 + RNE pack: dword j = P(k-pair start 8*(j>>1)+2*(j&1)+4*hi, col q=i32)
      unsigned Dw[8];
#pragma unroll
      for (int j = 0; j < 8; ++j) {
        float e0 = exp2f(s16[2 * j]);
        float e1 = exp2f(s16[2 * j + 1]);
        unsigned d;
        asm("v_cvt_pk_bf16_f32 %0, %1, %2" : "=v"(d) : "v"(e0), "v"(e1));
        Dw[j] = d;
      }
      // Half-swap repack into PV A-frags via permlane32_swap, then lsum + PV.
#pragma unroll
      for (int sl = 0; sl < 2; ++sl) {
        const int bb = sl * 4;
        unsigned x0 = Dw[bb + 0], y0 = Dw[bb + 2];
        unsigned x1 = Dw[bb + 1], y1 = Dw[bb + 3];
        asm("v_permlane32_swap_b32 %0, %1" : "+v"(x0), "+v"(y0));
        asm("v_permlane32_swap_b32 %0, %1" : "+v"(x1), "+v"(y1));
        uint4 u;
        u.x = x0;                        // e0,e1: k = 16*sl + 8*hi + {0,1}
        u.y = x1;                        // e2,e3: +2
        u.z = y0;                        // e4,e5: +4
        u.w = y1;                        // e6,e7: +6
        bf16x8 pf = __builtin_bit_cast(bf16x8, u);
        lacc = mfma32(pf, onesf, lacc);  // row-sum on the matrix pipe
        oacc0 = mfma32(pf, __builtin_bit_cast(bf16x8, vr[2 * t + sl][0]), oacc0);
        oacc1 = mfma32(pf, __builtin_bit_cast(bf16x8, vr[2 * t + sl][1]), oacc1);
      }
    }

    if (!last) {
      unsigned short* Kn = Kl + (cur ? 0 : BUFO);
      *(uint4*)&Kn[srow0 * KSTR + sseg] = a0;
      *(uint4*)&Kn[srow1 * KSTR + sseg] = a1;
    }
    cur ^= 1;
  }

  // Epilogue: lacc reg r holds l for the same q-row as oacc reg r.
#pragma unroll
  for (int r = 0; r < 16; ++r) {
    float linv = 1.0f / lacc[r];
    int q = q0 + (r & 3) + 8 * (r >> 2) + 4 * hi;
    size_t base = (size_t)(b * N_ + q) * C_ + h * 64 + i32;
    O[base] = (unsigned short)f2bs(oacc0[r] * linv);
    O[base + 32] = (unsigned short)f2bs(oacc1[r] * linv);
  }
}

extern "C" void kernel_launch(void* const* d_in, const int* in_sizes, int n_in,
                              void* d_out, int out_size, void* d_ws, size_t ws_size,
                              hipStream_t stream) {
  const float* x_q = (const float*)d_in[0];
  const float* x_k = (const float*)d_in[1];
  const float* x_v = (const float*)d_in[2];
  const float* x_u = (const float*)d_in[3];
  const float* Wq  = (const float*)d_in[4];
  const float* Wk  = (const float*)d_in[5];
  const float* Wv  = (const float*)d_in[6];
  const float* Wp  = (const float*)d_in[7];
  const float* bp  = (const float*)d_in[8];

  char* ws = (char*)d_ws;
  size_t off = 0;
  auto alloc = [&](size_t bytes) {
    char* p = ws + off;
    off += (bytes + 255) & ~(size_t)255;
    return p;
  };
  unsigned short* wq16 = (unsigned short*)alloc((size_t)C_ * C_ * 2);
  unsigned short* wk16 = (unsigned short*)alloc((size_t)C_ * C_ * 2);
  unsigned short* wv16 = (unsigned short*)alloc((size_t)C_ * C_ * 2);
  unsigned short* wp16 = (unsigned short*)alloc((size_t)C_ * C_ * 2);
  float*          ucp  = (float*)alloc((size_t)B_ * N_ * 4);
  unsigned short* xq16 = (unsigned short*)alloc((size_t)B_ * N_ * C_ * 2);
  unsigned short* xk16 = (unsigned short*)alloc((size_t)B_ * N_ * C_ * 2);
  unsigned short* xv16 = (unsigned short*)alloc((size_t)B_ * N_ * C_ * 2);
  unsigned short* q_s  = (unsigned short*)alloc((size_t)B_ * N_ * C_ * 2);
  unsigned short* k_s  = (unsigned short*)alloc((size_t)B_ * N_ * C_ * 2);
  unsigned short* vT   = (unsigned short*)alloc((size_t)B_ * N_ * C_ * 2);
  unsigned short* ao   = (unsigned short*)alloc((size_t)B_ * N_ * C_ * 2);

  prep_kernel<<<dim3(22784), 256, 0, stream>>>(x_q, x_k, x_v, x_u, Wq, Wk, Wv, Wp,
                                               xq16, xk16, xv16,
                                               wq16, wk16, wv16, wp16, ucp);
  gemm_qkv<<<dim3(1152), 256, 0, stream>>>(xq16, xk16, xv16, wq16, wk16, wv16,
                                           q_s, k_s, vT, ucp);
  attn_kernel<<<dim3(768), 256, 0, stream>>>(q_s, k_s, vT, ao);
  gemm_out<<<dim3(768), 256, 0, stream>>>(ao, wp16, (float*)d_out, bp);
}

// Round 4
// 290.491 us; speedup vs baseline: 1.0918x; 1.0918x over previous
//
#include <hip/hip_runtime.h>
#include <hip/hip_bf16.h>
#include <cstdint>

// Problem constants
#define B_ 4
#define N_ 2048
#define C_ 768
#define H_ 12
#define D_ 64
// SCALE = D^-0.5 = 0.125; folded exp2 scale = 0.125 * log2(e)
#define QSCALE 0.18033688011112042f

typedef __bf16 bf16x8 __attribute__((ext_vector_type(8)));
typedef float f32x4 __attribute__((ext_vector_type(4)));
typedef float f32x16 __attribute__((ext_vector_type(16)));

// RNE float -> bf16 bits (branchless; inputs are finite)
__device__ __forceinline__ unsigned f2bs(float x) {
  unsigned u = __builtin_bit_cast(unsigned, x);
  unsigned r = (u + 0x7fffu + ((u >> 16) & 1u)) >> 16;
  return r;
}

__device__ __forceinline__ bf16x8 ldb8(const unsigned short* p) {
  return __builtin_bit_cast(bf16x8, *(const uint4*)p);
}

__device__ __forceinline__ f32x4 mfma16(bf16x8 a, bf16x8 b, f32x4 c) {
  return __builtin_amdgcn_mfma_f32_16x16x32_bf16(a, b, c, 0, 0, 0);
}

__device__ __forceinline__ f32x16 mfma32(bf16x8 a, bf16x8 b, f32x16 c) {
  return __builtin_amdgcn_mfma_f32_32x32x16_bf16(a, b, c, 0, 0, 0);
}

// async global->LDS, 16B per lane. lds base must be wave-uniform; HW deposits
// lane i at lds + i*16 (m97/m104 semantics).
__device__ __forceinline__ void async16(const unsigned short* g, unsigned short* l) {
  __builtin_amdgcn_global_load_lds(
      (const __attribute__((address_space(1))) unsigned int*)g,
      (__attribute__((address_space(3))) unsigned int*)l, 16, 0, 0);
}

// ---------------- fused prep: x/W f32->bf16 casts + uc row means ----------------
// blocks [0,18432): convert x_q/x_k/x_v (6144 blocks each)
// blocks [18432,20736): convert Wq/Wk/Wv/Wp (576 blocks each)
// blocks [20736,22784): uc[row] = mean(x_u row) (2048 blocks, 4 rows each)
__global__ void prep_kernel(
    const float* __restrict__ xq, const float* __restrict__ xk,
    const float* __restrict__ xv, const float* __restrict__ xu,
    const float* __restrict__ Wq, const float* __restrict__ Wk,
    const float* __restrict__ Wv, const float* __restrict__ Wp,
    unsigned short* __restrict__ dxq, unsigned short* __restrict__ dxk,
    unsigned short* __restrict__ dxv,
    unsigned short* __restrict__ dwq, unsigned short* __restrict__ dwk,
    unsigned short* __restrict__ dwv, unsigned short* __restrict__ dwp,
    float* __restrict__ uc) {
  const int id = blockIdx.x;
  if (id < 18432) {
    const float* s = (id < 6144) ? xq : (id < 12288) ? xk : xv;
    unsigned short* d = (id < 6144) ? dxq : (id < 12288) ? dxk : dxv;
    int i = ((id % 6144) * 256 + threadIdx.x) * 4;
    float4 v = *(const float4*)(s + i);
    ushort4 h;
    h.x = (unsigned short)f2bs(v.x); h.y = (unsigned short)f2bs(v.y);
    h.z = (unsigned short)f2bs(v.z); h.w = (unsigned short)f2bs(v.w);
    *(ushort4*)(d + i) = h;
  } else if (id < 20736) {
    int sub = id - 18432;
    int which = sub / 576;
    const float* s = (which == 0) ? Wq : (which == 1) ? Wk : (which == 2) ? Wv : Wp;
    unsigned short* d = (which == 0) ? dwq : (which == 1) ? dwk : (which == 2) ? dwv : dwp;
    int i = ((sub % 576) * 256 + threadIdx.x) * 4;
    float4 v = *(const float4*)(s + i);
    ushort4 h;
    h.x = (unsigned short)f2bs(v.x); h.y = (unsigned short)f2bs(v.y);
    h.z = (unsigned short)f2bs(v.z); h.w = (unsigned short)f2bs(v.w);
    *(ushort4*)(d + i) = h;
  } else {
    int sub = id - 20736;
    int w = threadIdx.x >> 6, lane = threadIdx.x & 63;
    int row = sub * 4 + w;
    const float* p = xu + (size_t)row * C_;
    float s = 0.f;
#pragma unroll
    for (int i = 0; i < 3; ++i) {
      float4 v = *(const float4*)(p + (i * 64 + lane) * 4);
      s += v.x + v.y + v.z + v.w;
    }
#pragma unroll
    for (int off = 1; off < 64; off <<= 1) s += __shfl_xor(s, off);
    if (lane == 0) uc[row] = s * (1.f / 768.f);
  }
}

// ---------------- GEMM mainloop (128x128 tile, BK=64, async16 staging) -------------
// A [8192 x 768] bf16 row-major, W [768 x 768] bf16 row-major (NT gemm).
// LDS: two 32-col panels per BK=64 tile (panel kk at kk*4096 shorts, [row][32]).
// Granule g = s*256+tid: dest shorts [g*8..g*8+8), src row=(g>>2)&127,
// col=((g>>9)<<5)|((g&3)<<3).  (R5/R7-measured structure.)
__device__ __forceinline__ void gemm_mainloop(
    const unsigned short* __restrict__ A, const unsigned short* __restrict__ W,
    int m0, int n0, unsigned short* Al, unsigned short* Bl,
    int tid, int wm, int wn, int quad, int id15, f32x4 (*acc)[4]) {
  const int wb = tid & 192;                        // wave-uniform granule base
  const unsigned short* ap[4];
  const unsigned short* bp[4];
#pragma unroll
  for (int s = 0; s < 4; ++s) {
    int g = s * 256 + tid;
    int row = (g >> 2) & 127;
    int col = ((g >> 9) << 5) | ((g & 3) << 3);
    ap[s] = A + (size_t)(m0 + row) * C_ + col;
    bp[s] = W + (size_t)(n0 + row) * C_ + col;
  }

  for (int kt = 0; kt < C_; kt += 64) {
    __syncthreads();
#pragma unroll
    for (int s = 0; s < 4; ++s) {
      async16(ap[s] + kt, Al + (s * 256 + wb) * 8);
      async16(bp[s] + kt, Bl + (s * 256 + wb) * 8);
    }
    __syncthreads();

#pragma unroll
    for (int kk = 0; kk < 2; ++kk) {
      bf16x8 af[4], bfr[4];
#pragma unroll
      for (int i = 0; i < 4; ++i)
        af[i]  = ldb8(&Al[kk * 4096 + (wm + i * 16 + id15) * 32 + quad * 8]);
#pragma unroll
      for (int j = 0; j < 4; ++j)
        bfr[j] = ldb8(&Bl[kk * 4096 + (wn + j * 16 + id15) * 32 + quad * 8]);
#pragma unroll
      for (int i = 0; i < 4; ++i)
#pragma unroll
        for (int j = 0; j < 4; ++j)
          acc[i][j] = mfma16(af[i], bfr[j], acc[i][j]);
    }
  }
}

// ---------------- fused QKV projection (XCD-swizzled 1D grid, 1152 blocks) ---------
// Blocks sharing an A-tile (all 6 n) are placed on the SAME XCD so its L2 serves
// the A re-reads (R6 profile: FETCH 169 MB vs ~41 MB ideal = cross-XCD duplication).
// z=0: Q = x_q@Wq^T * QSCALE*uc; z=1: K; z=2: V^T via LDS transpose, coalesced.
#define TSTR 136   // transpose LDS row stride (shorts): 272 B, 16B-aligned rows
__global__ __launch_bounds__(256, 3) void gemm_qkv(
    const unsigned short* __restrict__ xq, const unsigned short* __restrict__ xk,
    const unsigned short* __restrict__ xv,
    const unsigned short* __restrict__ wq, const unsigned short* __restrict__ wk,
    const unsigned short* __restrict__ wv,
    unsigned short* __restrict__ oq, unsigned short* __restrict__ ok,
    unsigned short* __restrict__ ov, const float* __restrict__ uc) {
  __shared__ __align__(16) unsigned short S[128 * TSTR];   // 34816 B; aliases Al/Bl
  unsigned short* Al = S;
  unsigned short* Bl = S + 8192;
  const int tid = threadIdx.x;
  const int w = tid >> 6, lane = tid & 63, quad = lane >> 4, id15 = lane & 15;
  const int wm = (w >> 1) << 6, wn = (w & 1) << 6;
  // XCD swizzle: xcd = id&7; within an XCD, n varies fastest for fixed (z,m)
  const int id = blockIdx.x;
  const int xcd = id & 7, slot = id >> 3;          // slot 0..143
  const int n0 = (slot % 6) << 7;
  const int gz = xcd * 24 + slot / 6;              // 0..191 = (z,m) pairs
  const int z = gz >> 6, m0 = (gz & 63) << 7;

  const unsigned short* A = (z == 0) ? xq : (z == 1) ? xk : xv;
  const unsigned short* W = (z == 0) ? wq : (z == 1) ? wk : wv;

  f32x4 acc[4][4] = {};
  gemm_mainloop(A, W, m0, n0, Al, Bl, tid, wm, wn, quad, id15, acc);

  if (z == 2) {
    // transpose through LDS: S[gn_local][n_local], then coalesced row writes
    __syncthreads();
#pragma unroll
    for (int i = 0; i < 4; ++i)
#pragma unroll
      for (int j = 0; j < 4; ++j) {
        uint2 u;
        u.x = f2bs(acc[i][j][0]) | (f2bs(acc[i][j][1]) << 16);
        u.y = f2bs(acc[i][j][2]) | (f2bs(acc[i][j][3]) << 16);
        *(uint2*)&S[(wn + j * 16 + id15) * TSTR + wm + i * 16 + quad * 4] = u;
      }
    __syncthreads();
    const int b = m0 >> 11, nb = m0 & (N_ - 1);
#pragma unroll
    for (int s = 0; s < 8; ++s) {
      int c = s * 256 + tid;               // 2048 chunks of 8 shorts
      int row = c >> 4, o = (c & 15) << 3;
      *(uint4*)(ov + (size_t)(b * C_ + n0 + row) * N_ + nb + o) = *(const uint4*)&S[row * TSTR + o];
    }
    return;
  }

#pragma unroll
  for (int i = 0; i < 4; ++i) {
#pragma unroll
    for (int j = 0; j < 4; ++j) {
#pragma unroll
      for (int r = 0; r < 4; ++r) {
        int gm = m0 + wm + i * 16 + quad * 4 + r;   // global row (b*N + n)
        int gn = n0 + wn + j * 16 + id15;           // global out channel
        float v = acc[i][j][r];
        if (z == 0) {
          v *= QSCALE * uc[gm];
          oq[(size_t)gm * C_ + gn] = (unsigned short)f2bs(v);
        } else {
          ok[(size_t)gm * C_ + gn] = (unsigned short)f2bs(v);
        }
      }
    }
  }
}

// ---------------- output projection: out = ao@Wp^T + bp, f32 ----------------
// Tile 64(M) x 128(N), BK=64 -> 768 blocks = 3/CU (was 384 = 1.5/CU tail).
// XCD swizzle: same-A-tile blocks (6 n) on one XCD.
__global__ __launch_bounds__(256, 4) void gemm_out(
    const unsigned short* __restrict__ ao, const unsigned short* __restrict__ wp,
    float* __restrict__ out, const float* __restrict__ bias) {
  __shared__ __align__(16) unsigned short Al[64 * 64];
  __shared__ __align__(16) unsigned short Bl[128 * 64];
  const int tid = threadIdx.x;
  const int w = tid >> 6, lane = tid & 63, quad = lane >> 4, id15 = lane & 15;
  const int wm = (w >> 1) << 5, wn = (w & 1) << 6;
  const int id = blockIdx.x;
  const int xcd = id & 7, slot = id >> 3;          // slot 0..95
  const int n0 = (slot % 6) << 7;
  const int m0 = (xcd * 16 + slot / 6) << 6;       // m-tile 0..127

  const int wb = tid & 192;
  const unsigned short* ap[2];
#pragma unroll
  for (int s = 0; s < 2; ++s) {                    // A: 64x64 tile, 512 granules
    int g = s * 256 + tid;
    int row = (g >> 2) & 63;
    int col = ((g >> 8) << 5) | ((g & 3) << 3);
    ap[s] = ao + (size_t)(m0 + row) * C_ + col;
  }
  const unsigned short* bp[4];
#pragma unroll
  for (int s = 0; s < 4; ++s) {                    // B: 128x64 tile, 1024 granules
    int g = s * 256 + tid;
    int row = (g >> 2) & 127;
    int col = ((g >> 9) << 5) | ((g & 3) << 3);
    bp[s] = wp + (size_t)(n0 + row) * C_ + col;
  }

  f32x4 acc[2][4] = {};
  for (int kt = 0; kt < C_; kt += 64) {
    __syncthreads();
#pragma unroll
    for (int s = 0; s < 2; ++s) async16(ap[s] + kt, Al + (s * 256 + wb) * 8);
#pragma unroll
    for (int s = 0; s < 4; ++s) async16(bp[s] + kt, Bl + (s * 256 + wb) * 8);
    __syncthreads();

#pragma unroll
    for (int kk = 0; kk < 2; ++kk) {
      bf16x8 af[2], bfr[4];
#pragma unroll
      for (int i = 0; i < 2; ++i)
        af[i]  = ldb8(&Al[kk * 2048 + (wm + i * 16 + id15) * 32 + quad * 8]);
#pragma unroll
      for (int j = 0; j < 4; ++j)
        bfr[j] = ldb8(&Bl[kk * 4096 + (wn + j * 16 + id15) * 32 + quad * 8]);
#pragma unroll
      for (int i = 0; i < 2; ++i)
#pragma unroll
        for (int j = 0; j < 4; ++j)
          acc[i][j] = mfma16(af[i], bfr[j], acc[i][j]);
    }
  }

#pragma unroll
  for (int i = 0; i < 2; ++i) {
#pragma unroll
    for (int j = 0; j < 4; ++j) {
#pragma unroll
      for (int r = 0; r < 4; ++r) {
        int gm = m0 + wm + i * 16 + quad * 4 + r;
        int gn = n0 + wn + j * 16 + id15;
        out[(size_t)gm * C_ + gn] = acc[i][j][r] + bias[gn];
      }
    }
  }
}

// ---------------- Flash attention v4: LDS K+V dbuf, raw barrier, permlane ---------
// R2 post-mortem: direct-L2 V was a 4KB-stride lane gather (64 lines/instr) ->
// +25us. V must be staged through LDS (that IS the coalescer). R1 post-mortem:
// __syncthreads drains vmcnt(0) at the barrier, exposing next-tile load latency
// every iter. v4 = v2's coalesced K+V LDS double-buffer + v3's raw s_barrier with
// lgkmcnt-only drain: next-tile global loads issued at iter top stay in flight
// across the barrier and land in LDS after compute (vmcnt wait auto-inserted at
// the write). One barrier/iter. T5 setprio wraps the MFMA clusters.
// (R3 bench was an infra failure; this is v4 resubmitted with plain exp2f.)
// C/D layout (m74/m101): col=lane&31, row=(reg&3)+8*(reg>>2)+4*(lane>>5).
#define KSTR 72   // K/V LDS row stride (shorts): 144 B
#define VOFF (64 * KSTR)        // V panel offset within a buffer (shorts)
#define BUFO (2 * 64 * KSTR)    // double-buffer stride (shorts); LDS = 36864 B
__global__ __launch_bounds__(256, 3) void attn_kernel(
    const unsigned short* __restrict__ Q, const unsigned short* __restrict__ Kk,
    const unsigned short* __restrict__ Vt, unsigned short* __restrict__ O) {
  __shared__ __align__(16) unsigned short KV[2 * 2 * 64 * KSTR];  // 36864 B

  const int tid = threadIdx.x;
  const int w = tid >> 6, lane = tid & 63;
  const int i32 = lane & 31, hi = lane >> 5;
  const int id = blockIdx.x;
  const int xcd = id & 7, slot = id >> 3;          // slot 0..95
  const int bh = xcd * 6 + (slot >> 4);            // 0..47
  const int qt = slot & 15;
  const int b = bh / H_, h = bh % H_;
  const int q0 = qt * 128 + w * 32;                // 32 q-rows per wave

  // Q fragments (B-operand of QK^T): qf[s] = Q[q0+i32][d = s*16 + hi*8 + e]
  bf16x8 qf[4];
#pragma unroll
  for (int s = 0; s < 4; ++s)
    qf[s] = ldb8(Q + (size_t)(b * N_ + q0 + i32) * C_ + h * 64 + s * 16 + hi * 8);

  const uint4 onesu = {0x3F803F80u, 0x3F803F80u, 0x3F803F80u, 0x3F803F80u};
  const bf16x8 onesf = __builtin_bit_cast(bf16x8, onesu);

  f32x16 oacc0 = {}, oacc1 = {}, lacc = {};

  const size_t kbase = (size_t)(b * N_) * C_ + h * 64;
  const size_t vbase = (size_t)(b * C_ + h * 64) * N_;
  const int srow0 = tid >> 3, srow1 = 32 + (tid >> 3);
  const int sseg = (tid & 7) << 3;

  // Prologue: stage K+V tile 0 into buffer 0 (coalesced reg->LDS)
  {
    uint4 a0 = *(const uint4*)(Kk + kbase + (size_t)srow0 * C_ + sseg);
    uint4 a1 = *(const uint4*)(Kk + kbase + (size_t)srow1 * C_ + sseg);
    uint4 c0 = *(const uint4*)(Vt + vbase + (size_t)srow0 * N_ + sseg);
    uint4 c1 = *(const uint4*)(Vt + vbase + (size_t)srow1 * N_ + sseg);
    *(uint4*)&KV[srow0 * KSTR + sseg] = a0;
    *(uint4*)&KV[srow1 * KSTR + sseg] = a1;
    *(uint4*)&KV[VOFF + srow0 * KSTR + sseg] = c0;
    *(uint4*)&KV[VOFF + srow1 * KSTR + sseg] = c1;
  }

  int cur = 0;
  for (int kc = 0; kc < N_; kc += 64) {
    // next K+V tile -> regs, issued at iter top; they stay in flight across the
    // raw barrier (no vmcnt drain) and land in LDS after compute.
    const bool last = (kc + 64 >= N_);
    uint4 a0, a1, c0, c1;
    if (!last) {
      const int kcn = kc + 64;
      a0 = *(const uint4*)(Kk + kbase + (size_t)(kcn + srow0) * C_ + sseg);
      a1 = *(const uint4*)(Kk + kbase + (size_t)(kcn + srow1) * C_ + sseg);
      c0 = *(const uint4*)(Vt + vbase + (size_t)srow0 * N_ + kcn + sseg);
      c1 = *(const uint4*)(Vt + vbase + (size_t)srow1 * N_ + kcn + sseg);
    }

    // drain own LDS ops (prev writes + frag reads), then barrier. NO vmcnt drain.
    asm volatile("s_waitcnt lgkmcnt(0)" ::: "memory");
    __builtin_amdgcn_s_barrier();

    const unsigned short* Kc = KV + (cur ? BUFO : 0);
    const unsigned short* Vc = Kc + VOFF;
#pragma unroll
    for (int t = 0; t < 2; ++t) {        // k-row tile of 32 within the 64-row block
      // QK^T (S^T: rows = k, cols = q), contraction over D=64 in 4 ksteps
      f32x16 s16 = {};
      __builtin_amdgcn_s_setprio(1);
#pragma unroll
      for (int s = 0; s < 4; ++s) {
        bf16x8 kf = ldb8(Kc + (t * 32 + i32) * KSTR + s * 16 + hi * 8);
        s16 = mfma32(kf, qf[s], s16);
      }
      __builtin_amdgcn_s_setprio(0);
      // exp2 + RNE pack: dword j = P(k-pair start 8*(j>>1)+2*(j&1)+4*hi, col q=i32)
      unsigned Dw[8];
#pragma unroll
      for (int j = 0; j < 8; ++j) {
        float e0 = exp2f(s16[2 * j]);
        float e1 = exp2f(s16[2 * j + 1]);
        unsigned d;
        asm("v_cvt_pk_bf16_f32 %0, %1, %2" : "=v"(d) : "v"(e0), "v"(e1));
        Dw[j] = d;
      }
      // Half-swap repack into PV A-frags via permlane32_swap, then lsum + PV.
      __builtin_amdgcn_s_setprio(1);
#pragma unroll
      for (int sl = 0; sl < 2; ++sl) {
        const int bb = sl * 4;
        unsigned x0 = Dw[bb + 0], y0 = Dw[bb + 2];
        unsigned x1 = Dw[bb + 1], y1 = Dw[bb + 3];
        asm("v_permlane32_swap_b32 %0, %1" : "+v"(x0), "+v"(y0));
        asm("v_permlane32_swap_b32 %0, %1" : "+v"(x1), "+v"(y1));
        uint4 u;
        u.x = x0;                        // e0,e1: k = 16*sl + 8*hi + {0,1}
        u.y = x1;                        // e2,e3: +2
        u.z = y0;                        // e4,e5: +4
        u.w = y1;                        // e6,e7: +6
        bf16x8 pf = __builtin_bit_cast(bf16x8, u);
        lacc = mfma32(pf, onesf, lacc);  // row-sum on the matrix pipe
        bf16x8 v0 = ldb8(Vc + i32 * KSTR + (2 * t + sl) * 16 + hi * 8);
        bf16x8 v1 = ldb8(Vc + (32 + i32) * KSTR + (2 * t + sl) * 16 + hi * 8);
        oacc0 = mfma32(pf, v0, oacc0);
        oacc1 = mfma32(pf, v1, oacc1);
      }
      __builtin_amdgcn_s_setprio(0);
    }

    if (!last) {
      unsigned short* Kn = KV + (cur ? 0 : BUFO);
      *(uint4*)&Kn[srow0 * KSTR + sseg] = a0;
      *(uint4*)&Kn[srow1 * KSTR + sseg] = a1;
      *(uint4*)&Kn[VOFF + srow0 * KSTR + sseg] = c0;
      *(uint4*)&Kn[VOFF + srow1 * KSTR + sseg] = c1;
    }
    cur ^= 1;
  }

  // Epilogue: lacc reg r holds l for the same q-row as oacc reg r.
#pragma unroll
  for (int r = 0; r < 16; ++r) {
    float linv = 1.0f / lacc[r];
    int q = q0 + (r & 3) + 8 * (r >> 2) + 4 * hi;
    size_t base = (size_t)(b * N_ + q) * C_ + h * 64 + i32;
    O[base] = (unsigned short)f2bs(oacc0[r] * linv);
    O[base + 32] = (unsigned short)f2bs(oacc1[r] * linv);
  }
}

extern "C" void kernel_launch(void* const* d_in, const int* in_sizes, int n_in,
                              void* d_out, int out_size, void* d_ws, size_t ws_size,
                              hipStream_t stream) {
  const float* x_q = (const float*)d_in[0];
  const float* x_k = (const float*)d_in[1];
  const float* x_v = (const float*)d_in[2];
  const float* x_u = (const float*)d_in[3];
  const float* Wq  = (const float*)d_in[4];
  const float* Wk  = (const float*)d_in[5];
  const float* Wv  = (const float*)d_in[6];
  const float* Wp  = (const float*)d_in[7];
  const float* bp  = (const float*)d_in[8];

  char* ws = (char*)d_ws;
  size_t off = 0;
  auto alloc = [&](size_t bytes) {
    char* p = ws + off;
    off += (bytes + 255) & ~(size_t)255;
    return p;
  };
  unsigned short* wq16 = (unsigned short*)alloc((size_t)C_ * C_ * 2);
  unsigned short* wk16 = (unsigned short*)alloc((size_t)C_ * C_ * 2);
  unsigned short* wv16 = (unsigned short*)alloc((size_t)C_ * C_ * 2);
  unsigned short* wp16 = (unsigned short*)alloc((size_t)C_ * C_ * 2);
  float*          ucp  = (float*)alloc((size_t)B_ * N_ * 4);
  unsigned short* xq16 = (unsigned short*)alloc((size_t)B_ * N_ * C_ * 2);
  unsigned short* xk16 = (unsigned short*)alloc((size_t)B_ * N_ * C_ * 2);
  unsigned short* xv16 = (unsigned short*)alloc((size_t)B_ * N_ * C_ * 2);
  unsigned short* q_s  = (unsigned short*)alloc((size_t)B_ * N_ * C_ * 2);
  unsigned short* k_s  = (unsigned short*)alloc((size_t)B_ * N_ * C_ * 2);
  unsigned short* vT   = (unsigned short*)alloc((size_t)B_ * N_ * C_ * 2);
  unsigned short* ao   = (unsigned short*)alloc((size_t)B_ * N_ * C_ * 2);

  prep_kernel<<<dim3(22784), 256, 0, stream>>>(x_q, x_k, x_v, x_u, Wq, Wk, Wv, Wp,
                                               xq16, xk16, xv16,
                                               wq16, wk16, wv16, wp16, ucp);
  gemm_qkv<<<dim3(1152), 256, 0, stream>>>(xq16, xk16, xv16, wq16, wk16, wv16,
                                           q_s, k_s, vT, ucp);
  attn_kernel<<<dim3(768), 256, 0, stream>>>(q_s, k_s, vT, ao);
  gemm_out<<<dim3(768), 256, 0, stream>>>(ao, wp16, (float*)d_out, bp);
}